// Round 16
// baseline (348.886 us; speedup 1.0000x reference)
//
#include <hip/hip_runtime.h>
#include <hip/hip_bf16.h>

typedef __hip_bfloat16 bf16;
typedef __attribute__((ext_vector_type(8))) short bf16x8;   // 8 bf16 (4 VGPRs)
typedef __attribute__((ext_vector_type(4))) float f32x4;

#define T_LEN 2048
#define DMODEL 1024
#define DINNER 2048
#define DSTATE 16
#define LN_EPS 1e-5f
#define NCHUNK 128
#define CLEN 16     // NCHUNK * CLEN == T_LEN
#define SSTR 64     // ssm row stride (33 used, padded to 64)
#define PSEG 131072 // elems per split-K partial (2048*64)

#define GLOBAL_AS __attribute__((address_space(1)))
#define LDS_AS __attribute__((address_space(3)))

__device__ __forceinline__ void g2l16(void* lds, const void* g) {
    __builtin_amdgcn_global_load_lds((const GLOBAL_AS void*)g, (LDS_AS void*)lds, 16, 0, 0);
}

// ---------- weight preps + LayerNorm in ONE launch ----------
__global__ void prep_all(const float* __restrict__ Win, const float* __restrict__ Wout,
                         const float* __restrict__ Wx, const float* __restrict__ x,
                         const float* __restrict__ lng, const float* __restrict__ lnb,
                         bf16* __restrict__ WinT, bf16* __restrict__ WoutT,
                         bf16* __restrict__ WxT, bf16* __restrict__ xn) {
    __shared__ float t[32][33];
    int bid = blockIdx.x, tid = threadIdx.x;
    int tx = tid & 31, ty4 = (tid >> 5) * 4;
    if (bid < 4096) {               // W_in [1024][4096] -> WinT [4096][1024]
        int n0 = (bid & 127) * 32, k0 = (bid >> 7) * 32;
#pragma unroll
        for (int r = 0; r < 4; r++)
            t[ty4 + r][tx] = Win[(size_t)(k0 + ty4 + r) * 4096 + n0 + tx];
        __syncthreads();
#pragma unroll
        for (int r = 0; r < 4; r++)
            WinT[(size_t)(n0 + ty4 + r) * 1024 + k0 + tx] = __float2bfloat16(t[tx][ty4 + r]);
    } else if (bid < 6144) {        // W_out [2048][1024] -> WoutT [1024][2048]
        int b = bid - 4096;
        int n0 = (b & 31) * 32, k0 = (b >> 5) * 32;
#pragma unroll
        for (int r = 0; r < 4; r++)
            t[ty4 + r][tx] = Wout[(size_t)(k0 + ty4 + r) * 1024 + n0 + tx];
        __syncthreads();
#pragma unroll
        for (int r = 0; r < 4; r++)
            WoutT[(size_t)(n0 + ty4 + r) * 2048 + k0 + tx] = __float2bfloat16(t[tx][ty4 + r]);
    } else if (bid < 6656) {        // W_x [2048][33] -> WxT [64][2048], zero-pad
        int idx = (bid - 6144) * 256 + tid;
        int n = idx >> 11, k = idx & 2047;
        WxT[idx] = __float2bfloat16(n < 33 ? Wx[k * 33 + n] : 0.f);
    } else {                        // LayerNorm row
        int row = bid - 6656;
        const float* xr = x + (size_t)row * DMODEL;
        float v[4];
        float s = 0.f, q = 0.f;
#pragma unroll
        for (int i = 0; i < 4; i++) {
            v[i] = xr[tid + i * 256];
            s += v[i];
            q += v[i] * v[i];
        }
        __shared__ float sh_s[256], sh_q[256];
        sh_s[tid] = s; sh_q[tid] = q;
        __syncthreads();
        for (int st = 128; st > 0; st >>= 1) {
            if (tid < st) { sh_s[tid] += sh_s[tid + st]; sh_q[tid] += sh_q[tid + st]; }
            __syncthreads();
        }
        float mean = sh_s[0] * (1.f / DMODEL);
        float var  = sh_q[0] * (1.f / DMODEL) - mean * mean;
        float rstd = rsqrtf(var + LN_EPS);
#pragma unroll
        for (int i = 0; i < 4; i++) {
            int c = tid + i * 256;
            xn[(size_t)row * DMODEL + c] =
                __float2bfloat16((v[i] - mean) * rstd * lng[c] + lnb[c]);
        }
    }
}

// ---------- MFMA GEMM: C = A[M][lda](bf16) * Bt[N][lda](bf16)^T ----------
template <int BM, int BN, int WAVE_M, int WAVE_N, int WRITE_RESID, int OUT_BF16>
__global__ void gemm_mfma(const bf16* __restrict__ A, const bf16* __restrict__ Bt,
                          void* __restrict__ Cv, const float* __restrict__ resid,
                          int M, int N, int Kslice, int lda) {
    constexpr int WMsz = BM / WAVE_M;
    constexpr int WNsz = BN / WAVE_N;
    constexpr int TM = WMsz / 16;
    constexpr int TN = WNsz / 16;
    __shared__ short As[BM * 64];
    __shared__ short Bs[BN * 64];
    int tid = threadIdx.x;
    int lane = tid & 63, wave = tid >> 6;
    int wm = (wave / WAVE_N) * WMsz, wn = (wave % WAVE_N) * WNsz;
    int rowBase = blockIdx.y * BM, colBase = blockIdx.x * BN;
    int kbase = blockIdx.z * Kslice;

    f32x4 acc[TM][TN];
#pragma unroll
    for (int i = 0; i < TM; i++)
#pragma unroll
        for (int j = 0; j < TN; j++) acc[i][j] = f32x4{0.f, 0.f, 0.f, 0.f};

    int srow = tid >> 3;
    int cc = (tid & 7) ^ (srow & 7);
    const int ldsoff = tid * 16;

    for (int k0 = kbase; k0 < kbase + Kslice; k0 += 64) {
#pragma unroll
        for (int j = 0; j < BM / 32; j++)
            g2l16((char*)As + j * 4096 + ldsoff,
                  A + (size_t)(rowBase + j * 32 + srow) * lda + k0 + cc * 8);
#pragma unroll
        for (int j = 0; j < BN / 32; j++)
            g2l16((char*)Bs + j * 4096 + ldsoff,
                  Bt + (size_t)(colBase + j * 32 + srow) * lda + k0 + cc * 8);
        __syncthreads();
#pragma unroll
        for (int ks = 0; ks < 2; ks++) {
            bf16x8 af[TM], bfr[TN];
#pragma unroll
            for (int i = 0; i < TM; i++) {
                int row = wm + i * 16 + (lane & 15);
                int slot = (ks * 4 + (lane >> 4)) ^ (row & 7);
                af[i] = *(const bf16x8*)((const char*)As + row * 128 + slot * 16);
            }
#pragma unroll
            for (int j = 0; j < TN; j++) {
                int row = wn + j * 16 + (lane & 15);
                int slot = (ks * 4 + (lane >> 4)) ^ (row & 7);
                bfr[j] = *(const bf16x8*)((const char*)Bs + row * 128 + slot * 16);
            }
#pragma unroll
            for (int i = 0; i < TM; i++)
#pragma unroll
                for (int j = 0; j < TN; j++)
                    acc[i][j] = __builtin_amdgcn_mfma_f32_16x16x32_bf16(
                        af[i], bfr[j], acc[i][j], 0, 0, 0);
        }
        __syncthreads();
    }
    int rq = lane >> 4, cn = lane & 15;
    float* Cf = (float*)Cv + (size_t)blockIdx.z * M * N;
#pragma unroll
    for (int i = 0; i < TM; i++) {
#pragma unroll
        for (int j = 0; j < TN; j++) {
#pragma unroll
            for (int r = 0; r < 4; r++) {
                size_t row = rowBase + wm + i * 16 + rq * 4 + r;
                int col = colBase + wn + j * 16 + cn;
                float v = acc[i][j][r];
                if (WRITE_RESID) v += resid[row * N + col];
                if (OUT_BF16)
                    ((bf16*)Cv)[row * N + col] = __float2bfloat16(v);
                else
                    Cf[row * N + col] = v;
            }
        }
    }
}

// ---------- Causal depthwise conv(4) + SiLU ----------
__global__ void conv_silu(const bf16* __restrict__ xz, const float* __restrict__ cw,
                          const float* __restrict__ cb, bf16* __restrict__ xc) {
    int idx = blockIdx.x * 256 + threadIdx.x;
    int t = idx >> 11, d = idx & (DINNER - 1);
    float acc = cb[d];
#pragma unroll
    for (int k = 0; k < 4; k++) {
        int tt = t - 3 + k;
        if (tt >= 0) acc += (float)xz[(size_t)tt * (2 * DINNER) + d] * cw[d * 4 + k];
    }
    xc[idx] = __float2bfloat16(acc / (1.f + __expf(-acc)));
}

__device__ __forceinline__ float softplus_f(float pre) {
    return (pre > 20.f) ? pre : log1pf(__expf(pre));
}

// q^1..q^16 in a[0..15], log-depth
__device__ __forceinline__ void powtree(float q, float* a) {
    a[0] = q;
    a[1] = q * q;
    a[2] = a[1] * q;
    a[3] = a[1] * a[1];
#pragma unroll
    for (int j = 0; j < 4; j++) a[4 + j] = a[j] * a[3];
#pragma unroll
    for (int j = 0; j < 8; j++) a[8 + j] = a[j] * a[7];
}

// slab fill summing the 4 split-K partials
__device__ __forceinline__ void fill_slab(float (*slab)[SSTR], const float* parts,
                                          int t0, int tid) {
#pragma unroll
    for (int r = 0; r < 4; r++) {
        int idx = r * 256 + tid;   // 0..1023 = t*64 + col
        int off = (t0 << 6) + idx;
        slab[idx >> 6][idx & 63] = parts[off] + parts[off + PSEG] +
                                   parts[off + 2 * PSEG] + parts[off + 3 * PSEG];
    }
}

// ---------- Scan pass 1: also stores q (or dt in generic path) and dtxc ----------
__global__ __launch_bounds__(256, 4) void scan_pass1(
        const float* __restrict__ parts, const bf16* __restrict__ xc,
        const float* __restrict__ Wdt, const float* __restrict__ bdt,
        const float* __restrict__ Alog,
        float* __restrict__ P, float* __restrict__ S,
        float* __restrict__ qarr, float* __restrict__ dxarr) {
    __shared__ float slab[CLEN][SSTR];
    int tid = threadIdx.x;
    int d = blockIdx.x * 256 + tid;
    int c = blockIdx.y;
    int t0 = c * CLEN;
    fill_slab(slab, parts, t0, tid);
    float A[DSTATE], Pv[DSTATE], Sv[DSTATE];
    bool fast = true;
#pragma unroll
    for (int n = 0; n < DSTATE; n++) {
        A[n] = -__expf(Alog[d * DSTATE + n]);
        fast = fast && (fabsf(A[n] + (float)(n + 1)) < 1e-3f * (n + 1));
        Pv[n] = 1.f; Sv[n] = 0.f;
    }
    float wdt = Wdt[d], bd = bdt[d];
    __syncthreads();
    if (fast) {
        for (int i = 0; i < CLEN; i++) {
            float dt = softplus_f(slab[i][0] * wdt + bd);
            float dtxc = dt * (float)xc[(size_t)(t0 + i) * DINNER + d];
            float q = __expf(-dt);
            qarr[(size_t)(t0 + i) * DINNER + d] = q;
            dxarr[(size_t)(t0 + i) * DINNER + d] = dtxc;
            float a[DSTATE];
            powtree(q, a);
#pragma unroll
            for (int n = 0; n < DSTATE; n++) {
                Pv[n] *= a[n];
                Sv[n] = a[n] * Sv[n] + dtxc * slab[i][1 + n];
            }
        }
    } else {
        for (int i = 0; i < CLEN; i++) {
            float dt = softplus_f(slab[i][0] * wdt + bd);
            float dtxc = dt * (float)xc[(size_t)(t0 + i) * DINNER + d];
            qarr[(size_t)(t0 + i) * DINNER + d] = dt;    // generic path stores dt
            dxarr[(size_t)(t0 + i) * DINNER + d] = dtxc;
#pragma unroll
            for (int n = 0; n < DSTATE; n++) {
                float a = __expf(dt * A[n]);
                Pv[n] *= a;
                Sv[n] = a * Sv[n] + dtxc * slab[i][1 + n];
            }
        }
    }
    size_t base = (size_t)c * DINNER * DSTATE + d;   // [c][n][d]
#pragma unroll
    for (int n = 0; n < DSTATE; n++) {
        P[base + (size_t)n * DINNER] = Pv[n];
        S[base + (size_t)n * DINNER] = Sv[n];
    }
}

// ---------- Scan pass 2: sequential over chunks per (n,d) ----------
__global__ void scan_pass2(float* __restrict__ P, const float* __restrict__ S) {
    int idx = blockIdx.x * 256 + threadIdx.x;
    float H = 0.f;
#pragma unroll 4
    for (int c = 0; c < NCHUNK; c++) {
        size_t o = (size_t)c * DINNER * DSTATE + idx;
        float Pc = P[o], Sc = S[o];
        P[o] = H;
        H = Pc * H + Sc;
    }
}

// ---------- Scan pass 3: loads q/dtxc (no transcendentals on the h-chain) ----------
__global__ __launch_bounds__(256, 4) void scan_pass3(
        const float* __restrict__ parts, const bf16* __restrict__ xc,
        const bf16* __restrict__ xz,
        const float* __restrict__ Alog, const float* __restrict__ Dp,
        const float* __restrict__ Hst,
        const float* __restrict__ qarr, const float* __restrict__ dxarr,
        bf16* __restrict__ yf) {
    __shared__ float slab[CLEN][SSTR];
    int tid = threadIdx.x;
    int d = blockIdx.x * 256 + tid;
    int c = blockIdx.y;
    int t0 = c * CLEN;
    fill_slab(slab, parts, t0, tid);
    float A[DSTATE], h[DSTATE];
    bool fast = true;
    size_t base = (size_t)c * DINNER * DSTATE + d;
#pragma unroll
    for (int n = 0; n < DSTATE; n++) {
        A[n] = -__expf(Alog[d * DSTATE + n]);
        fast = fast && (fabsf(A[n] + (float)(n + 1)) < 1e-3f * (n + 1));
        h[n] = Hst[base + (size_t)n * DINNER];
    }
    float Dd = Dp[d];
    __syncthreads();
    if (fast) {
        for (int i = 0; i < CLEN; i++) {
            float q = qarr[(size_t)(t0 + i) * DINNER + d];
            float dtxc = dxarr[(size_t)(t0 + i) * DINNER + d];
            float a[DSTATE];
            powtree(q, a);
            float y0 = 0.f, y1 = 0.f, y2 = 0.f, y3 = 0.f;
#pragma unroll
            for (int n = 0; n < 4; n++) {
                h[n] = a[n] * h[n] + dtxc * slab[i][1 + n];
                y0 += h[n] * slab[i][17 + n];
                h[n + 4] = a[n + 4] * h[n + 4] + dtxc * slab[i][5 + n];
                y1 += h[n + 4] * slab[i][21 + n];
                h[n + 8] = a[n + 8] * h[n + 8] + dtxc * slab[i][9 + n];
                y2 += h[n + 8] * slab[i][25 + n];
                h[n + 12] = a[n + 12] * h[n + 12] + dtxc * slab[i][13 + n];
                y3 += h[n + 12] * slab[i][29 + n];
            }
            float y = (y0 + y1) + (y2 + y3);
            float xcv = (float)xc[(size_t)(t0 + i) * DINNER + d];
            float z = (float)xz[(size_t)(t0 + i) * (2 * DINNER) + DINNER + d];
            float sz = z / (1.f + __expf(-z));
            yf[(size_t)(t0 + i) * DINNER + d] = __float2bfloat16((y + xcv * Dd) * sz);
        }
    } else {
        for (int i = 0; i < CLEN; i++) {
            float dt = qarr[(size_t)(t0 + i) * DINNER + d];   // dt in generic path
            float dtxc = dxarr[(size_t)(t0 + i) * DINNER + d];
            float y = 0.f;
#pragma unroll
            for (int n = 0; n < DSTATE; n++) {
                float a = __expf(dt * A[n]);
                h[n] = a * h[n] + dtxc * slab[i][1 + n];
                y += h[n] * slab[i][17 + n];
            }
            float xcv = (float)xc[(size_t)(t0 + i) * DINNER + d];
            float z = (float)xz[(size_t)(t0 + i) * (2 * DINNER) + DINNER + d];
            float sz = z / (1.f + __expf(-z));
            yf[(size_t)(t0 + i) * DINNER + d] = __float2bfloat16((y + xcv * Dd) * sz);
        }
    }
}

extern "C" void kernel_launch(void* const* d_in, const int* in_sizes, int n_in,
                              void* d_out, int out_size, void* d_ws, size_t ws_size,
                              hipStream_t stream) {
    const float* x     = (const float*)d_in[0];
    const float* W_in  = (const float*)d_in[1];
    const float* convw = (const float*)d_in[2];
    const float* convb = (const float*)d_in[3];
    const float* W_x   = (const float*)d_in[4];
    const float* W_dt  = (const float*)d_in[5];
    const float* b_dt  = (const float*)d_in[6];
    const float* A_log = (const float*)d_in[7];
    const float* Dp    = (const float*)d_in[8];
    const float* W_out = (const float*)d_in[9];
    const float* ln_g  = (const float*)d_in[10];
    const float* ln_b  = (const float*)d_in[11];
    float* out = (float*)d_out;

    // 116 MB of the 256 MiB workspace; no aliasing.
    char* wsb = (char*)d_ws;
    bf16*  xn    = (bf16*)(wsb);                    //  4 MB
    bf16*  WinT  = (bf16*)(wsb + (4ull  << 20));    //  8 MB
    bf16*  WoutT = (bf16*)(wsb + (12ull << 20));    //  4 MB
    bf16*  WxT   = (bf16*)(wsb + (16ull << 20));    //  0.25 MB
    bf16*  xz    = (bf16*)(wsb + (17ull << 20));    // 16 MB
    bf16*  xc    = (bf16*)(wsb + (33ull << 20));    //  8 MB
    float* parts = (float*)(wsb + (41ull << 20));   //  2 MB (4 x 2048x64)
    float* P     = (float*)(wsb + (44ull << 20));   // 16 MB
    float* S     = (float*)(wsb + (60ull << 20));   // 16 MB
    bf16*  yf    = (bf16*)(wsb + (76ull << 20));    //  8 MB
    float* qarr  = (float*)(wsb + (84ull << 20));   // 16 MB
    float* dxarr = (float*)(wsb + (100ull << 20));  // 16 MB

    prep_all<<<8704, 256, 0, stream>>>(W_in, W_out, W_x, x, ln_g, ln_b,
                                       WinT, WoutT, WxT, xn);

    gemm_mfma<128, 128, 2, 2, 0, 1><<<dim3(4096 / 128, 2048 / 128), 256, 0, stream>>>(
        xn, WinT, xz, nullptr, 2048, 4096, 1024, 1024);

    conv_silu<<<(T_LEN * DINNER) / 256, 256, 0, stream>>>(xz, convw, convb, xc);

    gemm_mfma<32, 64, 2, 2, 0, 0><<<dim3(1, 2048 / 32, 4), 256, 0, stream>>>(
        xc, WxT, parts, nullptr, 2048, 64, 512, 2048);

    scan_pass1<<<dim3(DINNER / 256, NCHUNK), 256, 0, stream>>>(
        parts, xc, W_dt, b_dt, A_log, P, S, qarr, dxarr);
    scan_pass2<<<(DINNER * DSTATE) / 256, 256, 0, stream>>>(P, S);
    scan_pass3<<<dim3(DINNER / 256, NCHUNK), 256, 0, stream>>>(
        parts, xc, xz, A_log, Dp, P, qarr, dxarr, yf);

    gemm_mfma<64, 64, 2, 2, 1, 0><<<dim3(1024 / 64, 2048 / 64), 256, 0, stream>>>(
        yf, WoutT, out, x, 2048, 1024, 2048, 2048);
}

// Round 17
// 248.658 us; speedup vs baseline: 1.4031x; 1.4031x over previous
//
#include <hip/hip_runtime.h>
#include <hip/hip_bf16.h>

typedef __hip_bfloat16 bf16;
typedef __attribute__((ext_vector_type(8))) short bf16x8;   // 8 bf16 (4 VGPRs)
typedef __attribute__((ext_vector_type(4))) float f32x4;

#define T_LEN 2048
#define DMODEL 1024
#define DINNER 2048
#define DSTATE 16
#define LN_EPS 1e-5f
#define NCHUNK 128
#define CLEN 16     // NCHUNK * CLEN == T_LEN
#define SSTR 64     // ssm row stride (33 used, padded to 64)
#define PSEG 131072 // elems per split-K partial (2048*64)

#define GLOBAL_AS __attribute__((address_space(1)))
#define LDS_AS __attribute__((address_space(3)))

__device__ __forceinline__ void g2l16(void* lds, const void* g) {
    __builtin_amdgcn_global_load_lds((const GLOBAL_AS void*)g, (LDS_AS void*)lds, 16, 0, 0);
}

__device__ __forceinline__ float b2f(short s) {
    return __uint_as_float(((unsigned)(unsigned short)s) << 16);
}

// ---------- weight preps + LayerNorm in ONE launch ----------
__global__ void prep_all(const float* __restrict__ Win, const float* __restrict__ Wout,
                         const float* __restrict__ Wx, const float* __restrict__ x,
                         const float* __restrict__ lng, const float* __restrict__ lnb,
                         bf16* __restrict__ WinT, bf16* __restrict__ WoutT,
                         bf16* __restrict__ WxT, bf16* __restrict__ xn) {
    __shared__ float t[32][33];
    int bid = blockIdx.x, tid = threadIdx.x;
    int tx = tid & 31, ty4 = (tid >> 5) * 4;
    if (bid < 4096) {               // W_in [1024][4096] -> WinT [4096][1024]
        int n0 = (bid & 127) * 32, k0 = (bid >> 7) * 32;
#pragma unroll
        for (int r = 0; r < 4; r++)
            t[ty4 + r][tx] = Win[(size_t)(k0 + ty4 + r) * 4096 + n0 + tx];
        __syncthreads();
#pragma unroll
        for (int r = 0; r < 4; r++)
            WinT[(size_t)(n0 + ty4 + r) * 1024 + k0 + tx] = __float2bfloat16(t[tx][ty4 + r]);
    } else if (bid < 6144) {        // W_out [2048][1024] -> WoutT [1024][2048]
        int b = bid - 4096;
        int n0 = (b & 31) * 32, k0 = (b >> 5) * 32;
#pragma unroll
        for (int r = 0; r < 4; r++)
            t[ty4 + r][tx] = Wout[(size_t)(k0 + ty4 + r) * 1024 + n0 + tx];
        __syncthreads();
#pragma unroll
        for (int r = 0; r < 4; r++)
            WoutT[(size_t)(n0 + ty4 + r) * 2048 + k0 + tx] = __float2bfloat16(t[tx][ty4 + r]);
    } else if (bid < 6656) {        // W_x [2048][33] -> WxT [64][2048], zero-pad
        int idx = (bid - 6144) * 256 + tid;
        int n = idx >> 11, k = idx & 2047;
        WxT[idx] = __float2bfloat16(n < 33 ? Wx[k * 33 + n] : 0.f);
    } else {                        // LayerNorm row
        int row = bid - 6656;
        const float* xr = x + (size_t)row * DMODEL;
        float v[4];
        float s = 0.f, q = 0.f;
#pragma unroll
        for (int i = 0; i < 4; i++) {
            v[i] = xr[tid + i * 256];
            s += v[i];
            q += v[i] * v[i];
        }
        __shared__ float sh_s[256], sh_q[256];
        sh_s[tid] = s; sh_q[tid] = q;
        __syncthreads();
        for (int st = 128; st > 0; st >>= 1) {
            if (tid < st) { sh_s[tid] += sh_s[tid + st]; sh_q[tid] += sh_q[tid + st]; }
            __syncthreads();
        }
        float mean = sh_s[0] * (1.f / DMODEL);
        float var  = sh_q[0] * (1.f / DMODEL) - mean * mean;
        float rstd = rsqrtf(var + LN_EPS);
#pragma unroll
        for (int i = 0; i < 4; i++) {
            int c = tid + i * 256;
            xn[(size_t)row * DMODEL + c] =
                __float2bfloat16((v[i] - mean) * rstd * lng[c] + lnb[c]);
        }
    }
}

// ---------- MFMA GEMM: C = A[M][lda](bf16) * Bt[N][lda](bf16)^T ----------
template <int BM, int BN, int WAVE_M, int WAVE_N, int WRITE_RESID, int OUT_BF16>
__global__ void gemm_mfma(const bf16* __restrict__ A, const bf16* __restrict__ Bt,
                          void* __restrict__ Cv, const float* __restrict__ resid,
                          int M, int N, int Kslice, int lda) {
    constexpr int WMsz = BM / WAVE_M;
    constexpr int WNsz = BN / WAVE_N;
    constexpr int TM = WMsz / 16;
    constexpr int TN = WNsz / 16;
    __shared__ short As[BM * 64];
    __shared__ short Bs[BN * 64];
    int tid = threadIdx.x;
    int lane = tid & 63, wave = tid >> 6;
    int wm = (wave / WAVE_N) * WMsz, wn = (wave % WAVE_N) * WNsz;
    int rowBase = blockIdx.y * BM, colBase = blockIdx.x * BN;
    int kbase = blockIdx.z * Kslice;

    f32x4 acc[TM][TN];
#pragma unroll
    for (int i = 0; i < TM; i++)
#pragma unroll
        for (int j = 0; j < TN; j++) acc[i][j] = f32x4{0.f, 0.f, 0.f, 0.f};

    int srow = tid >> 3;
    int cc = (tid & 7) ^ (srow & 7);
    const int ldsoff = tid * 16;

    for (int k0 = kbase; k0 < kbase + Kslice; k0 += 64) {
#pragma unroll
        for (int j = 0; j < BM / 32; j++)
            g2l16((char*)As + j * 4096 + ldsoff,
                  A + (size_t)(rowBase + j * 32 + srow) * lda + k0 + cc * 8);
#pragma unroll
        for (int j = 0; j < BN / 32; j++)
            g2l16((char*)Bs + j * 4096 + ldsoff,
                  Bt + (size_t)(colBase + j * 32 + srow) * lda + k0 + cc * 8);
        __syncthreads();
#pragma unroll
        for (int ks = 0; ks < 2; ks++) {
            bf16x8 af[TM], bfr[TN];
#pragma unroll
            for (int i = 0; i < TM; i++) {
                int row = wm + i * 16 + (lane & 15);
                int slot = (ks * 4 + (lane >> 4)) ^ (row & 7);
                af[i] = *(const bf16x8*)((const char*)As + row * 128 + slot * 16);
            }
#pragma unroll
            for (int j = 0; j < TN; j++) {
                int row = wn + j * 16 + (lane & 15);
                int slot = (ks * 4 + (lane >> 4)) ^ (row & 7);
                bfr[j] = *(const bf16x8*)((const char*)Bs + row * 128 + slot * 16);
            }
#pragma unroll
            for (int i = 0; i < TM; i++)
#pragma unroll
                for (int j = 0; j < TN; j++)
                    acc[i][j] = __builtin_amdgcn_mfma_f32_16x16x32_bf16(
                        af[i], bfr[j], acc[i][j], 0, 0, 0);
        }
        __syncthreads();
    }
    int rq = lane >> 4, cn = lane & 15;
    float* Cf = (float*)Cv + (size_t)blockIdx.z * M * N;
#pragma unroll
    for (int i = 0; i < TM; i++) {
#pragma unroll
        for (int j = 0; j < TN; j++) {
#pragma unroll
            for (int r = 0; r < 4; r++) {
                size_t row = rowBase + wm + i * 16 + rq * 4 + r;
                int col = colBase + wn + j * 16 + cn;
                float v = acc[i][j][r];
                if (WRITE_RESID) v += resid[row * N + col];
                if (OUT_BF16)
                    ((bf16*)Cv)[row * N + col] = __float2bfloat16(v);
                else
                    Cf[row * N + col] = v;
            }
        }
    }
}

// ---------- Causal depthwise conv(4) + SiLU ----------
__global__ void conv_silu(const bf16* __restrict__ xz, const float* __restrict__ cw,
                          const float* __restrict__ cb, bf16* __restrict__ xc) {
    int idx = blockIdx.x * 256 + threadIdx.x;
    int t = idx >> 11, d = idx & (DINNER - 1);
    float acc = cb[d];
#pragma unroll
    for (int k = 0; k < 4; k++) {
        int tt = t - 3 + k;
        if (tt >= 0) acc += (float)xz[(size_t)tt * (2 * DINNER) + d] * cw[d * 4 + k];
    }
    xc[idx] = __float2bfloat16(acc / (1.f + __expf(-acc)));
}

__device__ __forceinline__ float softplus_f(float pre) {
    return (pre > 20.f) ? pre : log1pf(__expf(pre));
}

// q^1..q^16 in a[0..15], log-depth
__device__ __forceinline__ void powtree(float q, float* a) {
    a[0] = q;
    a[1] = q * q;
    a[2] = a[1] * q;
    a[3] = a[1] * a[1];
#pragma unroll
    for (int j = 0; j < 4; j++) a[4 + j] = a[j] * a[3];
#pragma unroll
    for (int j = 0; j < 8; j++) a[8 + j] = a[j] * a[7];
}

// slab fill summing the 4 split-K partials
__device__ __forceinline__ void fill_slab(float (*slab)[SSTR], const float* parts,
                                          int t0, int tid) {
#pragma unroll
    for (int r = 0; r < 4; r++) {
        int idx = r * 256 + tid;   // 0..1023 = t*64 + col
        int off = (t0 << 6) + idx;
        slab[idx >> 6][idx & 63] = parts[off] + parts[off + PSEG] +
                                   parts[off + 2 * PSEG] + parts[off + 3 * PSEG];
    }
}

// ---------- Scan pass 1: LDS slab + LDS xc prefetch ----------
__global__ __launch_bounds__(256, 4) void scan_pass1(
        const float* __restrict__ parts, const bf16* __restrict__ xc,
        const float* __restrict__ Wdt, const float* __restrict__ bdt,
        const float* __restrict__ Alog,
        float* __restrict__ P, float* __restrict__ S) {
    __shared__ float slab[CLEN][SSTR];   // 4 KB
    __shared__ short xcs[CLEN][256];     // 8 KB (2 lanes/word -> conflict-free)
    int tid = threadIdx.x;
    int d = blockIdx.x * 256 + tid;
    int c = blockIdx.y;
    int t0 = c * CLEN;
    fill_slab(slab, parts, t0, tid);
#pragma unroll
    for (int i = 0; i < CLEN; i++)
        xcs[i][tid] = ((const short*)xc)[(size_t)(t0 + i) * DINNER + d];
    float A[DSTATE], Pv[DSTATE], Sv[DSTATE];
    bool fast = true;
#pragma unroll
    for (int n = 0; n < DSTATE; n++) {
        A[n] = -__expf(Alog[d * DSTATE + n]);
        fast = fast && (fabsf(A[n] + (float)(n + 1)) < 1e-3f * (n + 1));
        Pv[n] = 1.f; Sv[n] = 0.f;
    }
    float wdt = Wdt[d], bd = bdt[d];
    __syncthreads();
    if (fast) {
        for (int i = 0; i < CLEN; i++) {
            float dt = softplus_f(slab[i][0] * wdt + bd);
            float dtxc = dt * b2f(xcs[i][tid]);
            float a[DSTATE];
            powtree(__expf(-dt), a);
#pragma unroll
            for (int n = 0; n < DSTATE; n++) {
                Pv[n] *= a[n];
                Sv[n] = a[n] * Sv[n] + dtxc * slab[i][1 + n];
            }
        }
    } else {
        for (int i = 0; i < CLEN; i++) {
            float dt = softplus_f(slab[i][0] * wdt + bd);
            float dtxc = dt * b2f(xcs[i][tid]);
#pragma unroll
            for (int n = 0; n < DSTATE; n++) {
                float a = __expf(dt * A[n]);
                Pv[n] *= a;
                Sv[n] = a * Sv[n] + dtxc * slab[i][1 + n];
            }
        }
    }
    size_t base = (size_t)c * DINNER * DSTATE + d;   // [c][n][d]
#pragma unroll
    for (int n = 0; n < DSTATE; n++) {
        P[base + (size_t)n * DINNER] = Pv[n];
        S[base + (size_t)n * DINNER] = Sv[n];
    }
}

// ---------- Scan pass 2: sequential over chunks per (n,d) ----------
__global__ void scan_pass2(float* __restrict__ P, const float* __restrict__ S) {
    int idx = blockIdx.x * 256 + threadIdx.x;
    float H = 0.f;
#pragma unroll 4
    for (int c = 0; c < NCHUNK; c++) {
        size_t o = (size_t)c * DINNER * DSTATE + idx;
        float Pc = P[o], Sc = S[o];
        P[o] = H;
        H = Pc * H + Sc;
    }
}

// ---------- Scan pass 3: LDS slab + LDS xc/z prefetch, fused epilogue ----------
__global__ __launch_bounds__(256, 4) void scan_pass3(
        const float* __restrict__ parts, const bf16* __restrict__ xc,
        const bf16* __restrict__ xz,
        const float* __restrict__ Wdt, const float* __restrict__ bdt,
        const float* __restrict__ Alog, const float* __restrict__ Dp,
        const float* __restrict__ Hst, bf16* __restrict__ yf) {
    __shared__ float slab[CLEN][SSTR];   // 4 KB
    __shared__ short xcs[CLEN][256];     // 8 KB
    __shared__ short zs[CLEN][256];      // 8 KB
    int tid = threadIdx.x;
    int d = blockIdx.x * 256 + tid;
    int c = blockIdx.y;
    int t0 = c * CLEN;
    fill_slab(slab, parts, t0, tid);
#pragma unroll
    for (int i = 0; i < CLEN; i++) {
        xcs[i][tid] = ((const short*)xc)[(size_t)(t0 + i) * DINNER + d];
        zs[i][tid]  = ((const short*)xz)[(size_t)(t0 + i) * (2 * DINNER) + DINNER + d];
    }
    float A[DSTATE], h[DSTATE];
    bool fast = true;
    size_t base = (size_t)c * DINNER * DSTATE + d;
#pragma unroll
    for (int n = 0; n < DSTATE; n++) {
        A[n] = -__expf(Alog[d * DSTATE + n]);
        fast = fast && (fabsf(A[n] + (float)(n + 1)) < 1e-3f * (n + 1));
        h[n] = Hst[base + (size_t)n * DINNER];
    }
    float wdt = Wdt[d], bd = bdt[d], Dd = Dp[d];
    __syncthreads();
    if (fast) {
        for (int i = 0; i < CLEN; i++) {
            float dt = softplus_f(slab[i][0] * wdt + bd);
            float xcv = b2f(xcs[i][tid]);
            float dtxc = dt * xcv;
            float a[DSTATE];
            powtree(__expf(-dt), a);
            float y0 = 0.f, y1 = 0.f, y2 = 0.f, y3 = 0.f;
#pragma unroll
            for (int n = 0; n < 4; n++) {
                h[n] = a[n] * h[n] + dtxc * slab[i][1 + n];
                y0 += h[n] * slab[i][17 + n];
                h[n + 4] = a[n + 4] * h[n + 4] + dtxc * slab[i][5 + n];
                y1 += h[n + 4] * slab[i][21 + n];
                h[n + 8] = a[n + 8] * h[n + 8] + dtxc * slab[i][9 + n];
                y2 += h[n + 8] * slab[i][25 + n];
                h[n + 12] = a[n + 12] * h[n + 12] + dtxc * slab[i][13 + n];
                y3 += h[n + 12] * slab[i][29 + n];
            }
            float y = (y0 + y1) + (y2 + y3);
            float z = b2f(zs[i][tid]);
            float sz = z / (1.f + __expf(-z));
            yf[(size_t)(t0 + i) * DINNER + d] = __float2bfloat16((y + xcv * Dd) * sz);
        }
    } else {
        for (int i = 0; i < CLEN; i++) {
            float dt = softplus_f(slab[i][0] * wdt + bd);
            float xcv = b2f(xcs[i][tid]);
            float dtxc = dt * xcv;
            float y = 0.f;
#pragma unroll
            for (int n = 0; n < DSTATE; n++) {
                float a = __expf(dt * A[n]);
                h[n] = a * h[n] + dtxc * slab[i][1 + n];
                y += h[n] * slab[i][17 + n];
            }
            float z = b2f(zs[i][tid]);
            float sz = z / (1.f + __expf(-z));
            yf[(size_t)(t0 + i) * DINNER + d] = __float2bfloat16((y + xcv * Dd) * sz);
        }
    }
}

extern "C" void kernel_launch(void* const* d_in, const int* in_sizes, int n_in,
                              void* d_out, int out_size, void* d_ws, size_t ws_size,
                              hipStream_t stream) {
    const float* x     = (const float*)d_in[0];
    const float* W_in  = (const float*)d_in[1];
    const float* convw = (const float*)d_in[2];
    const float* convb = (const float*)d_in[3];
    const float* W_x   = (const float*)d_in[4];
    const float* W_dt  = (const float*)d_in[5];
    const float* b_dt  = (const float*)d_in[6];
    const float* A_log = (const float*)d_in[7];
    const float* Dp    = (const float*)d_in[8];
    const float* W_out = (const float*)d_in[9];
    const float* ln_g  = (const float*)d_in[10];
    const float* ln_b  = (const float*)d_in[11];
    float* out = (float*)d_out;

    // 84 MB of the 256 MiB workspace; no aliasing.
    char* wsb = (char*)d_ws;
    bf16*  xn    = (bf16*)(wsb);                    //  4 MB
    bf16*  WinT  = (bf16*)(wsb + (4ull  << 20));    //  8 MB
    bf16*  WoutT = (bf16*)(wsb + (12ull << 20));    //  4 MB
    bf16*  WxT   = (bf16*)(wsb + (16ull << 20));    //  0.25 MB
    bf16*  xz    = (bf16*)(wsb + (17ull << 20));    // 16 MB
    bf16*  xc    = (bf16*)(wsb + (33ull << 20));    //  8 MB
    float* parts = (float*)(wsb + (41ull << 20));   //  2 MB (4 x 2048x64)
    float* P     = (float*)(wsb + (44ull << 20));   // 16 MB
    float* S     = (float*)(wsb + (60ull << 20));   // 16 MB
    bf16*  yf    = (bf16*)(wsb + (76ull << 20));    //  8 MB

    prep_all<<<8704, 256, 0, stream>>>(W_in, W_out, W_x, x, ln_g, ln_b,
                                       WinT, WoutT, WxT, xn);

    gemm_mfma<128, 128, 2, 2, 0, 1><<<dim3(4096 / 128, 2048 / 128), 256, 0, stream>>>(
        xn, WinT, xz, nullptr, 2048, 4096, 1024, 1024);

    conv_silu<<<(T_LEN * DINNER) / 256, 256, 0, stream>>>(xz, convw, convb, xc);

    gemm_mfma<32, 64, 2, 2, 0, 0><<<dim3(1, 2048 / 32, 4), 256, 0, stream>>>(
        xc, WxT, parts, nullptr, 2048, 64, 512, 2048);

    scan_pass1<<<dim3(DINNER / 256, NCHUNK), 256, 0, stream>>>(
        parts, xc, W_dt, b_dt, A_log, P, S);
    scan_pass2<<<(DINNER * DSTATE) / 256, 256, 0, stream>>>(P, S);
    scan_pass3<<<dim3(DINNER / 256, NCHUNK), 256, 0, stream>>>(
        parts, xc, xz, W_dt, b_dt, A_log, Dp, P, yf);

    gemm_mfma<64, 64, 2, 2, 1, 0><<<dim3(1024 / 64, 2048 / 64), 256, 0, stream>>>(
        yf, WoutT, out, x, 2048, 1024, 2048, 2048);
}